// Round 5
// baseline (696.836 us; speedup 1.0000x reference)
//
#include <hip/hip_runtime.h>
#include <hip/hip_bf16.h>
#include <math.h>

typedef unsigned int uint;
typedef __bf16 bf16_t;
typedef bf16_t bf16x8 __attribute__((ext_vector_type(8)));
typedef float f32x4 __attribute__((ext_vector_type(4)));

__device__ inline float2 bf2_unpack(uint u) {
    union { uint i; float f; } a, b;
    a.i = u << 16;
    b.i = u & 0xffff0000u;
    return make_float2(a.f, b.f);
}

__device__ inline uint bf2_pack(float x, float y) {
    __hip_bfloat162 h;
    h.x = __float2bfloat16(x);
    h.y = __float2bfloat16(y);
    return *(uint*)&h;
}

__device__ inline void store_out(float* p, float v) { *p = v; }
__device__ inline void store_out(__hip_bfloat16* p, float v) { *p = __float2bfloat16(v); }

// ---------------- CSR build ----------------
__global__ __launch_bounds__(256) void k_count(const int* __restrict__ ei, int* __restrict__ indeg, int E) {
    int e = blockIdx.x * 256 + threadIdx.x;
    if (e < E) atomicAdd(&indeg[ei[E + e]], 1);
}

__global__ __launch_bounds__(1024) void k_scan(const int* __restrict__ indeg, int* __restrict__ off, int n) {
    __shared__ int tmp[1024];
    int t = threadIdx.x;
    int per = (n + 1023) >> 10;
    int s0 = t * per, s1 = s0 + per; if (s1 > n) s1 = n;
    int sum = 0;
    for (int i = s0; i < s1; ++i) sum += indeg[i];
    tmp[t] = sum;
    __syncthreads();
    for (int d = 1; d < 1024; d <<= 1) {
        int a = (t >= d) ? tmp[t - d] : 0;
        __syncthreads();
        tmp[t] += a;
        __syncthreads();
    }
    int carry = tmp[t] - sum;  // exclusive prefix
    for (int i = s0; i < s1; ++i) { off[i] = carry; carry += indeg[i]; }
    if (t == 1023) off[n] = tmp[1023];
}

__global__ __launch_bounds__(256) void k_fill(const int* __restrict__ ei, const int* __restrict__ off,
                                              int* __restrict__ cursor, int* __restrict__ col, int E) {
    int e = blockIdx.x * 256 + threadIdx.x;
    if (e < E) {
        int d = ei[E + e];
        int p = atomicAdd(&cursor[d], 1);
        col[off[d] + p] = ei[e];
    }
}

__global__ __launch_bounds__(256) void k_dinv(const int* __restrict__ indeg, float* __restrict__ dinv, int n) {
    int i = blockIdx.x * 256 + threadIdx.x;
    if (i < n) dinv[i] = rsqrtf((float)(indeg[i] + 1));  // self-loop adds 1
}

// ---------------- fp32 -> bf16 weight conversion (6 x 128x128 mats) ----------------
__global__ __launch_bounds__(256) void k_cvt6(const float* __restrict__ s0, const float* __restrict__ s1,
                                              const float* __restrict__ s2, const float* __restrict__ s3,
                                              const float* __restrict__ s4, const float* __restrict__ s5,
                                              __hip_bfloat16* __restrict__ dst) {
    int i = blockIdx.x * 256 + threadIdx.x;
    if (i >= 6 * 16384) return;
    int m = i >> 14;
    const float* s = (m == 0) ? s0 : (m == 1) ? s1 : (m == 2) ? s2 : (m == 3) ? s3 : (m == 4) ? s4 : s5;
    dst[i] = __float2bfloat16(s[i & 16383]);
}

// ---------------- scalar linear for FI=32 (embed), bf16 out ----------------
template<int FI, bool BIAS, bool RELU, typename OUT>
__global__ __launch_bounds__(256) void k_linear(const float* __restrict__ x, const float* __restrict__ W,
                                                const float* __restrict__ b, OUT* __restrict__ y, int n) {
    __shared__ float4 Wt4[(FI / 4) * 128];
    __shared__ float4 xl[2][FI / 4];
    int t = threadIdx.x & 127;
    int h = threadIdx.x >> 7;
    {
        const float4* Wrow = (const float4*)(W + (size_t)t * FI);
        #pragma unroll
        for (int k4 = h * (FI / 8); k4 < (h + 1) * (FI / 8); ++k4) Wt4[k4 * 128 + t] = Wrow[k4];
    }
    float bias = 0.f;
    if (BIAS) bias = b[t];
    __syncthreads();
    for (int n0 = blockIdx.x * 2; n0 < n; n0 += gridDim.x * 2) {
        int nn = n0 + h;
        if (nn < n && t < FI / 4) xl[h][t] = ((const float4*)(x + (size_t)nn * FI))[t];
        __syncthreads();
        if (nn < n) {
            float acc = bias;
            #pragma unroll
            for (int k4 = 0; k4 < FI / 4; ++k4) {
                float4 xv = xl[h][k4];
                float4 wv = Wt4[k4 * 128 + t];
                acc += xv.x * wv.x + xv.y * wv.y + xv.z * wv.z + xv.w * wv.w;
            }
            if (RELU) acc = fmaxf(acc, 0.f);
            store_out(&y[(size_t)nn * 128 + t], acc);
        }
        __syncthreads();
    }
}

// ---------------- MFMA linear with per-row dinv prescale ----------------
__global__ __launch_bounds__(256) void k_lin_mfma_scale(const __hip_bfloat16* __restrict__ X,
                                                        const __hip_bfloat16* __restrict__ W,
                                                        const float* __restrict__ dinv,
                                                        __hip_bfloat16* __restrict__ y, int n) {
    int wave = threadIdx.x >> 6, lane = threadIdx.x & 63;
    int r0 = blockIdx.x * 64 + wave * 16;
    if (r0 >= n) return;
    int mrow = r0 + (lane & 15);
    if (mrow >= n) mrow = n - 1;
    int kk4 = lane >> 4;
    const bf16x8* xr = (const bf16x8*)((const bf16_t*)X + (size_t)mrow * 128);
    bf16x8 a0 = xr[0 * 4 + kk4];
    bf16x8 a1 = xr[1 * 4 + kk4];
    bf16x8 a2 = xr[2 * 4 + kk4];
    bf16x8 a3 = xr[3 * 4 + kk4];
    int orow = (lane >> 4) * 4;
    int ocol = lane & 15;
    float dv[4];
    #pragma unroll
    for (int j = 0; j < 4; ++j) {
        int row = r0 + orow + j;
        dv[j] = (row < n) ? dinv[row] : 0.f;
    }
    #pragma unroll
    for (int c = 0; c < 8; ++c) {
        const bf16x8* wr = (const bf16x8*)((const bf16_t*)W + (size_t)(c * 16 + (lane & 15)) * 128);
        bf16x8 b0 = wr[0 * 4 + kk4];
        bf16x8 b1 = wr[1 * 4 + kk4];
        bf16x8 b2 = wr[2 * 4 + kk4];
        bf16x8 b3 = wr[3 * 4 + kk4];
        f32x4 acc = {0.f, 0.f, 0.f, 0.f};
        acc = __builtin_amdgcn_mfma_f32_16x16x32_bf16(a0, b0, acc, 0, 0, 0);
        acc = __builtin_amdgcn_mfma_f32_16x16x32_bf16(a1, b1, acc, 0, 0, 0);
        acc = __builtin_amdgcn_mfma_f32_16x16x32_bf16(a2, b2, acc, 0, 0, 0);
        acc = __builtin_amdgcn_mfma_f32_16x16x32_bf16(a3, b3, acc, 0, 0, 0);
        int gcol = c * 16 + ocol;
        #pragma unroll
        for (int j = 0; j < 4; ++j) {
            int row = r0 + orow + j;
            if (row < n) store_out(&y[(size_t)row * 128 + gcol], acc[j] * dv[j]);
        }
    }
}

// ---------------- fused q/k/v/skip MFMA ----------------
__global__ __launch_bounds__(256) void k_qkvs_mfma(const __hip_bfloat16* __restrict__ X,
                                                   const __hip_bfloat16* __restrict__ W4,
                                                   const float* __restrict__ bq, const float* __restrict__ bk,
                                                   const float* __restrict__ bv, const float* __restrict__ bs,
                                                   float* __restrict__ Cq, __hip_bfloat16* __restrict__ KV,
                                                   float* __restrict__ Bb, int n) {
    int wave = threadIdx.x >> 6, lane = threadIdx.x & 63;
    int r0 = blockIdx.x * 64 + wave * 16;
    if (r0 >= n) return;
    int mrow = r0 + (lane & 15);
    if (mrow >= n) mrow = n - 1;
    int kk4 = lane >> 4;
    const bf16x8* xr = (const bf16x8*)((const bf16_t*)X + (size_t)mrow * 128);
    bf16x8 a0 = xr[0 * 4 + kk4];
    bf16x8 a1 = xr[1 * 4 + kk4];
    bf16x8 a2 = xr[2 * 4 + kk4];
    bf16x8 a3 = xr[3 * 4 + kk4];
    int orow = (lane >> 4) * 4;
    int ocol = lane & 15;
    #pragma unroll
    for (int m = 0; m < 4; ++m) {
        const bf16_t* Wm = (const bf16_t*)W4 + (size_t)m * 16384;
        const float* bias = (m == 0) ? bq : (m == 1) ? bk : (m == 2) ? bv : bs;
        #pragma unroll
        for (int c = 0; c < 8; ++c) {
            const bf16x8* wr = (const bf16x8*)(Wm + (size_t)(c * 16 + (lane & 15)) * 128);
            bf16x8 b0 = wr[0 * 4 + kk4];
            bf16x8 b1 = wr[1 * 4 + kk4];
            bf16x8 b2 = wr[2 * 4 + kk4];
            bf16x8 b3 = wr[3 * 4 + kk4];
            f32x4 acc = {0.f, 0.f, 0.f, 0.f};
            acc = __builtin_amdgcn_mfma_f32_16x16x32_bf16(a0, b0, acc, 0, 0, 0);
            acc = __builtin_amdgcn_mfma_f32_16x16x32_bf16(a1, b1, acc, 0, 0, 0);
            acc = __builtin_amdgcn_mfma_f32_16x16x32_bf16(a2, b2, acc, 0, 0, 0);
            acc = __builtin_amdgcn_mfma_f32_16x16x32_bf16(a3, b3, acc, 0, 0, 0);
            int gcol = c * 16 + ocol;
            float bb = bias[gcol];
            #pragma unroll
            for (int j = 0; j < 4; ++j) {
                int row = r0 + orow + j;
                if (row >= n) continue;
                float v = acc[j] + bb;
                if (m == 0) Cq[(size_t)row * 128 + gcol] = v * 0.25f;
                else if (m == 1) store_out(&KV[(size_t)row * 256 + gcol], v);
                else if (m == 2) store_out(&KV[(size_t)row * 256 + 128 + gcol], v);
                else Bb[(size_t)row * 128 + gcol] = v;
            }
        }
    }
}

// ---------------- GCN aggregation: 2 nodes/wave, uint2 loads, predicated unroll-4 ----------------
// y = relu(dinv[dst] * (xw'[self] + sum_nbrs xw'[s]) + b), bf16 out. xw' prescaled by src dinv.
__global__ __launch_bounds__(256) void k_gcn_agg(const uint* __restrict__ xw, const int* __restrict__ off,
                                                 const int* __restrict__ col, const float* __restrict__ dinv,
                                                 const float* __restrict__ bias, uint2* __restrict__ y, int n) {
    int wid = (blockIdx.x * 256 + threadIdx.x) >> 6;
    int lane = threadIdx.x & 63;
    int sub = lane >> 5, l32 = lane & 31;        // lane handles feats [4*l32, 4*l32+4) of node nd
    int nd = wid * 2 + sub;
    int ndc = (nd < n) ? nd : (n - 1);
    float di = dinv[ndc];
    const uint2* x2 = (const uint2*)xw;          // row = 32 uint2
    uint2 su = x2[((size_t)ndc << 5) + l32];
    float2 sa = bf2_unpack(su.x), sb = bf2_unpack(su.y);
    float acc0 = sa.x, acc1 = sa.y, acc2 = sb.x, acc3 = sb.y;
    int i = off[ndc];
    int i1 = (nd < n) ? off[ndc + 1] : i;
    int iclamp = (i1 > 0) ? (i1 - 1) : 0;
    while (__any(i < i1)) {
        bool v0 = i < i1, v1 = i + 1 < i1, v2 = i + 2 < i1, v3 = i + 3 < i1;
        int j0 = v0 ? i : iclamp;
        int j1 = v1 ? i + 1 : iclamp;
        int j2 = v2 ? i + 2 : iclamp;
        int j3 = v3 ? i + 3 : iclamp;
        int s0 = col[j0], s1 = col[j1], s2 = col[j2], s3 = col[j3];
        uint2 u0 = x2[((size_t)s0 << 5) + l32];
        uint2 u1 = x2[((size_t)s1 << 5) + l32];
        uint2 u2 = x2[((size_t)s2 << 5) + l32];
        uint2 u3 = x2[((size_t)s3 << 5) + l32];
        if (v0) { float2 p = bf2_unpack(u0.x), r = bf2_unpack(u0.y); acc0 += p.x; acc1 += p.y; acc2 += r.x; acc3 += r.y; }
        if (v1) { float2 p = bf2_unpack(u1.x), r = bf2_unpack(u1.y); acc0 += p.x; acc1 += p.y; acc2 += r.x; acc3 += r.y; }
        if (v2) { float2 p = bf2_unpack(u2.x), r = bf2_unpack(u2.y); acc0 += p.x; acc1 += p.y; acc2 += r.x; acc3 += r.y; }
        if (v3) { float2 p = bf2_unpack(u3.x), r = bf2_unpack(u3.y); acc0 += p.x; acc1 += p.y; acc2 += r.x; acc3 += r.y; }
        i += 4;
    }
    if (nd < n) {
        float4 b4 = ((const float4*)bias)[l32];
        uint o0 = bf2_pack(fmaxf(di * acc0 + b4.x, 0.f), fmaxf(di * acc1 + b4.y, 0.f));
        uint o1 = bf2_pack(fmaxf(di * acc2 + b4.z, 0.f), fmaxf(di * acc3 + b4.w, 0.f));
        y[((size_t)nd << 5) + l32] = make_uint2(o0, o1);
    }
}

// ---------------- attention: head-per-lane, 8 dst/wave, defer-max online softmax ----------------
// lane = (g=lane>>3: dst sub, h=lane&7: head). q prescaled by 0.25. KV row = 128 uints (k:0..63, v:64..127).
__global__ __launch_bounds__(256) void k_attn(const float* __restrict__ q, const uint* __restrict__ kv,
                                              const int* __restrict__ off, const int* __restrict__ col,
                                              float* __restrict__ io, int n) {
    int wid = (blockIdx.x * 256 + threadIdx.x) >> 6;
    int lane = threadIdx.x & 63;
    int g = lane >> 3, h = lane & 7;
    int dst = wid * 8 + g;
    int dc = (dst < n) ? dst : (n - 1);
    float qf[16];
    {
        const float4* q4 = (const float4*)(q + (size_t)dc * 128 + h * 16);
        #pragma unroll
        for (int j = 0; j < 4; ++j) {
            float4 t = q4[j];
            qf[4 * j] = t.x; qf[4 * j + 1] = t.y; qf[4 * j + 2] = t.z; qf[4 * j + 3] = t.w;
        }
    }
    float acc[16];
    #pragma unroll
    for (int j = 0; j < 16; ++j) acc[j] = 0.f;
    float m = -INFINITY, s = 0.f;
    int i = off[dc];
    int i1 = (dst < n) ? off[dc + 1] : i;
    int iclamp = (i1 > 0) ? (i1 - 1) : 0;
    int h8 = h * 8;
    while (__any(i < i1)) {
        bool act = i < i1;
        int idx = act ? i : iclamp;
        int src = col[idx];
        const uint* row = kv + ((size_t)(uint)src << 7);
        uint4 ka = *(const uint4*)(row + h8);
        uint4 kb = *(const uint4*)(row + h8 + 4);
        uint4 va = *(const uint4*)(row + 64 + h8);
        uint4 vb = *(const uint4*)(row + 64 + h8 + 4);
        uint ku[8] = {ka.x, ka.y, ka.z, ka.w, kb.x, kb.y, kb.z, kb.w};
        float l = 0.f;
        #pragma unroll
        for (int j = 0; j < 8; ++j) {
            float2 kf = bf2_unpack(ku[j]);
            l = fmaf(qf[2 * j], kf.x, l);
            l = fmaf(qf[2 * j + 1], kf.y, l);
        }
        if (!act) l = -INFINITY;
        if (__any(l > m + 8.f)) {          // defer-max: rescale only when max grows >8
            float mn = fmaxf(m, l);
            float corr = __expf(m - mn);   // 1 for lanes not growing; 0 on first edge (m=-inf)
            s *= corr;
            #pragma unroll
            for (int j = 0; j < 16; ++j) acc[j] *= corr;
            m = mn;
        }
        float e = act ? __expf(l - m) : 0.f;   // bounded by e^8
        s += e;
        uint vu[8] = {va.x, va.y, va.z, va.w, vb.x, vb.y, vb.z, vb.w};
        #pragma unroll
        for (int j = 0; j < 8; ++j) {
            float2 vf = bf2_unpack(vu[j]);
            acc[2 * j] = fmaf(e, vf.x, acc[2 * j]);
            acc[2 * j + 1] = fmaf(e, vf.y, acc[2 * j + 1]);
        }
        i += act ? 1 : 0;
    }
    if (dst < n) {
        float inv = 1.f / fmaxf(s, 1e-16f);
        float4* o4 = (float4*)(io + (size_t)dst * 128 + h * 16);
        #pragma unroll
        for (int j = 0; j < 4; ++j) {
            float4 t = o4[j];
            t.x += acc[4 * j] * inv;
            t.y += acc[4 * j + 1] * inv;
            t.z += acc[4 * j + 2] * inv;
            t.w += acc[4 * j + 3] * inv;
            o4[j] = t;
        }
    }
}

// ---------------- mean-pool per graph (batch sorted), 64 nodes/block ----------------
__global__ __launch_bounds__(128) void k_pool(const float* __restrict__ x, const int* __restrict__ batch,
                                              float* __restrict__ gsum, float* __restrict__ cnt, int n) {
    int t = threadIdx.x;
    int start = blockIdx.x * 64;
    int end = start + 64; if (end > n) end = n;
    if (start >= n) return;
    int cur = batch[start];
    float acc = 0.f;
    int run = 0;
    for (int nn = start; nn < end; ++nn) {
        int g = batch[nn];
        if (g != cur) {
            atomicAdd(&gsum[cur * 128 + t], acc);
            if (t == 0) atomicAdd(&cnt[cur], (float)run);
            acc = 0.f; run = 0; cur = g;
        }
        acc += x[(size_t)nn * 128 + t];
        run++;
    }
    atomicAdd(&gsum[cur * 128 + t], acc);
    if (t == 0) atomicAdd(&cnt[cur], (float)run);
}

// ---------------- FiLM + LSTM + LayerNorm + dueling heads, one block per graph ----------------
__global__ __launch_bounds__(128) void k_final(
    const float* __restrict__ gsum, const float* __restrict__ cnt, const float* __restrict__ w,
    const float* __restrict__ Wgam, const float* __restrict__ bgam,
    const float* __restrict__ Wbet, const float* __restrict__ bbet,
    const float* __restrict__ hprev, const float* __restrict__ cprev,
    const float* __restrict__ Wih, const float* __restrict__ bih,
    const float* __restrict__ Whh, const float* __restrict__ bhh,
    const float* __restrict__ lng, const float* __restrict__ lnb,
    const float* __restrict__ Wa1, const float* __restrict__ ba1,
    const float* __restrict__ Wa2, const float* __restrict__ ba2,
    const float* __restrict__ Wv1, const float* __restrict__ bv1,
    const float* __restrict__ Wv2, const float* __restrict__ bv2,
    float* __restrict__ out_qv, float* __restrict__ out_h, float* __restrict__ out_c) {
    int g = blockIdx.x, t = threadIdx.x;
    __shared__ __align__(16) float ge[128], hp[128], hn[128], r1[128], a1s[128], red[128];
    __shared__ float adv[16], val[2], mu_s, var_s;

    float w0 = w[g * 2 + 0], w1 = w[g * 2 + 1];
    float c = fmaxf(cnt[g], 1.f);
    float mn = gsum[g * 128 + t] / c;
    float gam = w0 * Wgam[2 * t] + w1 * Wgam[2 * t + 1] + bgam[t];
    float bet = w0 * Wbet[2 * t] + w1 * Wbet[2 * t + 1] + bbet[t];
    ge[t] = (1.f + gam) * mn + bet;
    hp[t] = hprev[g * 128 + t];
    __syncthreads();

    float gi = bih[t] + bhh[t];
    float gf = bih[128 + t] + bhh[128 + t];
    float gg = bih[256 + t] + bhh[256 + t];
    float go = bih[384 + t] + bhh[384 + t];
    {
        const float4* ge4 = (const float4*)ge;
        const float4* hp4 = (const float4*)hp;
        const float4* Ai = (const float4*)(Wih + (size_t)t * 128);
        const float4* Af = (const float4*)(Wih + (size_t)(128 + t) * 128);
        const float4* Ag = (const float4*)(Wih + (size_t)(256 + t) * 128);
        const float4* Ao = (const float4*)(Wih + (size_t)(384 + t) * 128);
        const float4* Hi = (const float4*)(Whh + (size_t)t * 128);
        const float4* Hf = (const float4*)(Whh + (size_t)(128 + t) * 128);
        const float4* Hg = (const float4*)(Whh + (size_t)(256 + t) * 128);
        const float4* Ho = (const float4*)(Whh + (size_t)(384 + t) * 128);
        #pragma unroll 4
        for (int k4 = 0; k4 < 32; ++k4) {
            float4 a = ge4[k4], h4 = hp4[k4], u;
            u = Ai[k4]; gi += a.x * u.x + a.y * u.y + a.z * u.z + a.w * u.w;
            u = Hi[k4]; gi += h4.x * u.x + h4.y * u.y + h4.z * u.z + h4.w * u.w;
            u = Af[k4]; gf += a.x * u.x + a.y * u.y + a.z * u.z + a.w * u.w;
            u = Hf[k4]; gf += h4.x * u.x + h4.y * u.y + h4.z * u.z + h4.w * u.w;
            u = Ag[k4]; gg += a.x * u.x + a.y * u.y + a.z * u.z + a.w * u.w;
            u = Hg[k4]; gg += h4.x * u.x + h4.y * u.y + h4.z * u.z + h4.w * u.w;
            u = Ao[k4]; go += a.x * u.x + a.y * u.y + a.z * u.z + a.w * u.w;
            u = Ho[k4]; go += h4.x * u.x + h4.y * u.y + h4.z * u.z + h4.w * u.w;
        }
    }
    float ig = 1.f / (1.f + __expf(-gi));
    float fg = 1.f / (1.f + __expf(-gf));
    float gc = tanhf(gg);
    float og = 1.f / (1.f + __expf(-go));
    float craw = fg * cprev[g * 128 + t] + ig * gc;
    float hraw = og * tanhf(craw);
    out_c[g * 128 + t] = fminf(fmaxf(craw, -1e6f), 1e6f);

    red[t] = hraw;
    __syncthreads();
    for (int s2 = 64; s2 > 0; s2 >>= 1) { if (t < s2) red[t] += red[t + s2]; __syncthreads(); }
    if (t == 0) mu_s = red[0] * (1.f / 128.f);
    __syncthreads();
    float mu = mu_s;
    float d = hraw - mu;
    red[t] = d * d;
    __syncthreads();
    for (int s2 = 64; s2 > 0; s2 >>= 1) { if (t < s2) red[t] += red[t + s2]; __syncthreads(); }
    if (t == 0) var_s = red[0] * (1.f / 128.f);
    __syncthreads();
    float hv = d * rsqrtf(var_s + 1e-5f) * lng[t] + lnb[t];
    hn[t] = hv;
    out_h[g * 128 + t] = hv;
    __syncthreads();

    float accv = bv1[t], acca = ba1[t];
    {
        const float4* hn4 = (const float4*)hn;
        const float4* V1 = (const float4*)(Wv1 + (size_t)t * 128);
        const float4* A1 = (const float4*)(Wa1 + (size_t)t * 128);
        #pragma unroll 4
        for (int k4 = 0; k4 < 32; ++k4) {
            float4 hh = hn4[k4], u;
            u = V1[k4]; accv += hh.x * u.x + hh.y * u.y + hh.z * u.z + hh.w * u.w;
            u = A1[k4]; acca += hh.x * u.x + hh.y * u.y + hh.z * u.z + hh.w * u.w;
        }
    }
    r1[t] = fmaxf(accv, 0.f);
    a1s[t] = fmaxf(acca, 0.f);
    __syncthreads();
    if (t < 2) {
        float s = bv2[t];
        const float4* V2 = (const float4*)(Wv2 + (size_t)t * 128);
        const float4* r4 = (const float4*)r1;
        for (int k4 = 0; k4 < 32; ++k4) { float4 u = V2[k4], rr = r4[k4]; s += rr.x * u.x + rr.y * u.y + rr.z * u.z + rr.w * u.w; }
        val[t] = s;
    }
    if (t < 14) {
        float s = ba2[t];
        const float4* A2 = (const float4*)(Wa2 + (size_t)t * 128);
        const float4* a4 = (const float4*)a1s;
        for (int k4 = 0; k4 < 32; ++k4) { float4 u = A2[k4], aa = a4[k4]; s += aa.x * u.x + aa.y * u.y + aa.z * u.z + aa.w * u.w; }
        adv[t] = s;
    }
    __syncthreads();
    if (t < 14) {
        int o = t & 1;
        float mo = (adv[o] + adv[o + 2] + adv[o + 4] + adv[o + 6] + adv[o + 8] + adv[o + 10] + adv[o + 12]) * (1.f / 7.f);
        float qq = val[o] + adv[t] - mo;
        if (isnan(qq)) qq = 0.f;
        qq = fminf(fmaxf(qq, -100.f), 100.f);
        out_qv[g * 14 + t] = qq;
    }
}

extern "C" void kernel_launch(void* const* d_in, const int* in_sizes, int n_in,
                              void* d_out, int out_size, void* d_ws, size_t ws_size,
                              hipStream_t stream) {
    const float* nf    = (const float*)d_in[0];
    const int*   ei    = (const int*)d_in[1];
    const int*   batch = (const int*)d_in[2];
    const float* w     = (const float*)d_in[3];
    const float* hprev = (const float*)d_in[4];
    const float* cprev = (const float*)d_in[5];
    const float* W_emb = (const float*)d_in[6];  const float* b_emb = (const float*)d_in[7];
    const float* W_g1  = (const float*)d_in[8];  const float* b_g1  = (const float*)d_in[9];
    const float* W_g2  = (const float*)d_in[10]; const float* b_g2  = (const float*)d_in[11];
    const float* Wq    = (const float*)d_in[12]; const float* bq    = (const float*)d_in[13];
    const float* Wk    = (const float*)d_in[14]; const float* bk    = (const float*)d_in[15];
    const float* Wv    = (const float*)d_in[16]; const float* bv    = (const float*)d_in[17];
    const float* Wskip = (const float*)d_in[18]; const float* bskip = (const float*)d_in[19];
    const float* Wgam  = (const float*)d_in[20]; const float* bgam  = (const float*)d_in[21];
    const float* Wbet  = (const float*)d_in[22]; const float* bbet  = (const float*)d_in[23];
    const float* Wih   = (const float*)d_in[24]; const float* bih   = (const float*)d_in[25];
    const float* Whh   = (const float*)d_in[26]; const float* bhh   = (const float*)d_in[27];
    const float* lng   = (const float*)d_in[28]; const float* lnb   = (const float*)d_in[29];
    const float* Wa1   = (const float*)d_in[30]; const float* ba1   = (const float*)d_in[31];
    const float* Wa2   = (const float*)d_in[32]; const float* ba2   = (const float*)d_in[33];
    const float* Wv1   = (const float*)d_in[34]; const float* bv1   = (const float*)d_in[35];
    const float* Wv2   = (const float*)d_in[36]; const float* bv2   = (const float*)d_in[37];

    int N = in_sizes[2];
    int E = in_sizes[1] / 2;
    int B = in_sizes[4] / 128;

    char* p = (char*)d_ws;
    auto alloc = [&](size_t bytes) { char* r = p; p += (bytes + 511) & ~(size_t)511; return r; };
    int*   indeg  = (int*)alloc((size_t)N * 4);
    int*   cursor = (int*)alloc((size_t)N * 4);
    float* gsum   = (float*)alloc((size_t)B * 128 * 4);
    float* cnt    = (float*)alloc((size_t)B * 4);
    size_t zbytes = (size_t)(p - (char*)d_ws);   // region zeroed each call
    int*   off    = (int*)alloc((size_t)(N + 1) * 4);
    int*   col    = (int*)alloc((size_t)E * 4);
    float* dinv   = (float*)alloc((size_t)N * 4);
    __hip_bfloat16* Wc  = (__hip_bfloat16*)alloc((size_t)6 * 16384 * 2);  // bf16 weights: g1,g2,q,k,v,skip
    __hip_bfloat16* X0b = (__hip_bfloat16*)alloc((size_t)N * 128 * 2);    // x0 / x2
    __hip_bfloat16* X1b = (__hip_bfloat16*)alloc((size_t)N * 128 * 2);    // x1
    __hip_bfloat16* XWb = (__hip_bfloat16*)alloc((size_t)N * 128 * 2);    // xw scratch (prescaled)
    __hip_bfloat16* KV  = (__hip_bfloat16*)alloc((size_t)N * 256 * 2);    // interleaved k|v
    float* Cq = (float*)alloc((size_t)N * 128 * 4);
    float* Bb = (float*)alloc((size_t)N * 128 * 4);
    if ((size_t)(p - (char*)d_ws) > ws_size) return;

    hipMemsetAsync(d_ws, 0, zbytes, stream);

    const __hip_bfloat16* Wg1b  = Wc + 0 * 16384;
    const __hip_bfloat16* Wg2b  = Wc + 1 * 16384;
    const __hip_bfloat16* Wqkvs = Wc + 2 * 16384;   // q,k,v,skip contiguous
    k_cvt6<<<384, 256, 0, stream>>>(W_g1, W_g2, Wq, Wk, Wv, Wskip, Wc);

    int gE = (E + 255) / 256;
    k_count<<<gE, 256, 0, stream>>>(ei, indeg, E);
    k_scan<<<1, 1024, 0, stream>>>(indeg, off, N);
    k_fill<<<gE, 256, 0, stream>>>(ei, off, cursor, col, E);
    k_dinv<<<(N + 255) / 256, 256, 0, stream>>>(indeg, dinv, N);

    int gG = (N + 7) / 8;       // gcn: 4 waves/block x 2 nodes/wave
    int gA = (N + 31) / 32;     // attn: 4 waves/block x 8 dst/wave
    int gM = (N + 63) / 64;     // MFMA kernels: 64 rows/block

    k_linear<32, true, true, __hip_bfloat16><<<2048, 256, 0, stream>>>(nf, W_emb, b_emb, X0b, N);   // x0 bf16
    k_lin_mfma_scale<<<gM, 256, 0, stream>>>(X0b, Wg1b, dinv, XWb, N);                              // xw1' = xw1*dinv
    k_gcn_agg<<<gG, 256, 0, stream>>>((const uint*)XWb, off, col, dinv, b_g1, (uint2*)X1b, N);      // x1
    k_lin_mfma_scale<<<gM, 256, 0, stream>>>(X1b, Wg2b, dinv, XWb, N);                              // xw2'
    k_gcn_agg<<<gG, 256, 0, stream>>>((const uint*)XWb, off, col, dinv, b_g2, (uint2*)X0b, N);      // x2

    k_qkvs_mfma<<<gM, 256, 0, stream>>>(X0b, Wqkvs, bq, bk, bv, bskip, Cq, KV, Bb, N);              // q,KV,skip
    k_attn<<<gA, 256, 0, stream>>>(Cq, (const uint*)KV, off, col, Bb, N);                           // Bb += attn

    k_pool<<<gM, 128, 0, stream>>>(Bb, batch, gsum, cnt, N);

    float* out_qv = (float*)d_out;
    float* out_h  = out_qv + (size_t)B * 14;
    float* out_c  = out_h + (size_t)B * 128;
    k_final<<<B, 128, 0, stream>>>(gsum, cnt, w, Wgam, bgam, Wbet, bbet, hprev, cprev,
                                   Wih, bih, Whh, bhh, lng, lnb,
                                   Wa1, ba1, Wa2, ba2, Wv1, bv1, Wv2, bv2,
                                   out_qv, out_h, out_c);
}

// Round 6
// 640.493 us; speedup vs baseline: 1.0880x; 1.0880x over previous
//
#include <hip/hip_runtime.h>
#include <hip/hip_bf16.h>
#include <math.h>

typedef unsigned int uint;
typedef __bf16 bf16_t;
typedef bf16_t bf16x8 __attribute__((ext_vector_type(8)));
typedef float f32x4 __attribute__((ext_vector_type(4)));

__device__ inline float2 bf2_unpack(uint u) {
    union { uint i; float f; } a, b;
    a.i = u << 16;
    b.i = u & 0xffff0000u;
    return make_float2(a.f, b.f);
}

__device__ inline void store_out(float* p, float v) { *p = v; }
__device__ inline void store_out(__hip_bfloat16* p, float v) { *p = __float2bfloat16(v); }

// ---------------- CSR build ----------------
__global__ __launch_bounds__(256) void k_count(const int* __restrict__ ei, int* __restrict__ indeg, int E) {
    int e = blockIdx.x * 256 + threadIdx.x;
    if (e < E) atomicAdd(&indeg[ei[E + e]], 1);
}

__global__ __launch_bounds__(1024) void k_scan(const int* __restrict__ indeg, int* __restrict__ off, int n) {
    __shared__ int tmp[1024];
    int t = threadIdx.x;
    int per = (n + 1023) >> 10;
    int s0 = t * per, s1 = s0 + per; if (s1 > n) s1 = n;
    int sum = 0;
    for (int i = s0; i < s1; ++i) sum += indeg[i];
    tmp[t] = sum;
    __syncthreads();
    for (int d = 1; d < 1024; d <<= 1) {
        int a = (t >= d) ? tmp[t - d] : 0;
        __syncthreads();
        tmp[t] += a;
        __syncthreads();
    }
    int carry = tmp[t] - sum;  // exclusive prefix
    for (int i = s0; i < s1; ++i) { off[i] = carry; carry += indeg[i]; }
    if (t == 1023) off[n] = tmp[1023];
}

__global__ __launch_bounds__(256) void k_fill(const int* __restrict__ ei, const int* __restrict__ off,
                                              int* __restrict__ cursor, int* __restrict__ col, int E) {
    int e = blockIdx.x * 256 + threadIdx.x;
    if (e < E) {
        int d = ei[E + e];
        int p = atomicAdd(&cursor[d], 1);
        col[off[d] + p] = ei[e];
    }
}

__global__ __launch_bounds__(256) void k_dinv(const int* __restrict__ indeg, float* __restrict__ dinv, int n) {
    int i = blockIdx.x * 256 + threadIdx.x;
    if (i < n) dinv[i] = rsqrtf((float)(indeg[i] + 1));  // self-loop adds 1
}

// ---------------- fp32 -> bf16 weight conversion (6 x 128x128 mats) ----------------
__global__ __launch_bounds__(256) void k_cvt6(const float* __restrict__ s0, const float* __restrict__ s1,
                                              const float* __restrict__ s2, const float* __restrict__ s3,
                                              const float* __restrict__ s4, const float* __restrict__ s5,
                                              __hip_bfloat16* __restrict__ dst) {
    int i = blockIdx.x * 256 + threadIdx.x;
    if (i >= 6 * 16384) return;
    int m = i >> 14;
    const float* s = (m == 0) ? s0 : (m == 1) ? s1 : (m == 2) ? s2 : (m == 3) ? s3 : (m == 4) ? s4 : s5;
    dst[i] = __float2bfloat16(s[i & 16383]);
}

// ---------------- scalar linear for FI=32 (embed), bf16 out ----------------
template<int FI, bool BIAS, bool RELU, typename OUT>
__global__ __launch_bounds__(256) void k_linear(const float* __restrict__ x, const float* __restrict__ W,
                                                const float* __restrict__ b, OUT* __restrict__ y, int n) {
    __shared__ float4 Wt4[(FI / 4) * 128];
    __shared__ float4 xl[2][FI / 4];
    int t = threadIdx.x & 127;
    int h = threadIdx.x >> 7;
    {
        const float4* Wrow = (const float4*)(W + (size_t)t * FI);
        #pragma unroll
        for (int k4 = h * (FI / 8); k4 < (h + 1) * (FI / 8); ++k4) Wt4[k4 * 128 + t] = Wrow[k4];
    }
    float bias = 0.f;
    if (BIAS) bias = b[t];
    __syncthreads();
    for (int n0 = blockIdx.x * 2; n0 < n; n0 += gridDim.x * 2) {
        int nn = n0 + h;
        if (nn < n && t < FI / 4) xl[h][t] = ((const float4*)(x + (size_t)nn * FI))[t];
        __syncthreads();
        if (nn < n) {
            float acc = bias;
            #pragma unroll
            for (int k4 = 0; k4 < FI / 4; ++k4) {
                float4 xv = xl[h][k4];
                float4 wv = Wt4[k4 * 128 + t];
                acc += xv.x * wv.x + xv.y * wv.y + xv.z * wv.z + xv.w * wv.w;
            }
            if (RELU) acc = fmaxf(acc, 0.f);
            store_out(&y[(size_t)nn * 128 + t], acc);
        }
        __syncthreads();
    }
}

// ---------------- MFMA linear with per-row dinv prescale ----------------
__global__ __launch_bounds__(256) void k_lin_mfma_scale(const __hip_bfloat16* __restrict__ X,
                                                        const __hip_bfloat16* __restrict__ W,
                                                        const float* __restrict__ dinv,
                                                        __hip_bfloat16* __restrict__ y, int n) {
    int wave = threadIdx.x >> 6, lane = threadIdx.x & 63;
    int r0 = blockIdx.x * 64 + wave * 16;
    if (r0 >= n) return;
    int mrow = r0 + (lane & 15);
    if (mrow >= n) mrow = n - 1;
    int kk4 = lane >> 4;
    const bf16x8* xr = (const bf16x8*)((const bf16_t*)X + (size_t)mrow * 128);
    bf16x8 a0 = xr[0 * 4 + kk4];
    bf16x8 a1 = xr[1 * 4 + kk4];
    bf16x8 a2 = xr[2 * 4 + kk4];
    bf16x8 a3 = xr[3 * 4 + kk4];
    int orow = (lane >> 4) * 4;
    int ocol = lane & 15;
    float dv[4];
    #pragma unroll
    for (int j = 0; j < 4; ++j) {
        int row = r0 + orow + j;
        dv[j] = (row < n) ? dinv[row] : 0.f;
    }
    #pragma unroll
    for (int c = 0; c < 8; ++c) {
        const bf16x8* wr = (const bf16x8*)((const bf16_t*)W + (size_t)(c * 16 + (lane & 15)) * 128);
        bf16x8 b0 = wr[0 * 4 + kk4];
        bf16x8 b1 = wr[1 * 4 + kk4];
        bf16x8 b2 = wr[2 * 4 + kk4];
        bf16x8 b3 = wr[3 * 4 + kk4];
        f32x4 acc = {0.f, 0.f, 0.f, 0.f};
        acc = __builtin_amdgcn_mfma_f32_16x16x32_bf16(a0, b0, acc, 0, 0, 0);
        acc = __builtin_amdgcn_mfma_f32_16x16x32_bf16(a1, b1, acc, 0, 0, 0);
        acc = __builtin_amdgcn_mfma_f32_16x16x32_bf16(a2, b2, acc, 0, 0, 0);
        acc = __builtin_amdgcn_mfma_f32_16x16x32_bf16(a3, b3, acc, 0, 0, 0);
        int gcol = c * 16 + ocol;
        #pragma unroll
        for (int j = 0; j < 4; ++j) {
            int row = r0 + orow + j;
            if (row < n) store_out(&y[(size_t)row * 128 + gcol], acc[j] * dv[j]);
        }
    }
}

// ---------------- fused q/k/v/skip MFMA ----------------
__global__ __launch_bounds__(256) void k_qkvs_mfma(const __hip_bfloat16* __restrict__ X,
                                                   const __hip_bfloat16* __restrict__ W4,
                                                   const float* __restrict__ bq, const float* __restrict__ bk,
                                                   const float* __restrict__ bv, const float* __restrict__ bs,
                                                   float* __restrict__ Cq, __hip_bfloat16* __restrict__ KV,
                                                   float* __restrict__ Bb, int n) {
    int wave = threadIdx.x >> 6, lane = threadIdx.x & 63;
    int r0 = blockIdx.x * 64 + wave * 16;
    if (r0 >= n) return;
    int mrow = r0 + (lane & 15);
    if (mrow >= n) mrow = n - 1;
    int kk4 = lane >> 4;
    const bf16x8* xr = (const bf16x8*)((const bf16_t*)X + (size_t)mrow * 128);
    bf16x8 a0 = xr[0 * 4 + kk4];
    bf16x8 a1 = xr[1 * 4 + kk4];
    bf16x8 a2 = xr[2 * 4 + kk4];
    bf16x8 a3 = xr[3 * 4 + kk4];
    int orow = (lane >> 4) * 4;
    int ocol = lane & 15;
    #pragma unroll
    for (int m = 0; m < 4; ++m) {
        const bf16_t* Wm = (const bf16_t*)W4 + (size_t)m * 16384;
        const float* bias = (m == 0) ? bq : (m == 1) ? bk : (m == 2) ? bv : bs;
        #pragma unroll
        for (int c = 0; c < 8; ++c) {
            const bf16x8* wr = (const bf16x8*)(Wm + (size_t)(c * 16 + (lane & 15)) * 128);
            bf16x8 b0 = wr[0 * 4 + kk4];
            bf16x8 b1 = wr[1 * 4 + kk4];
            bf16x8 b2 = wr[2 * 4 + kk4];
            bf16x8 b3 = wr[3 * 4 + kk4];
            f32x4 acc = {0.f, 0.f, 0.f, 0.f};
            acc = __builtin_amdgcn_mfma_f32_16x16x32_bf16(a0, b0, acc, 0, 0, 0);
            acc = __builtin_amdgcn_mfma_f32_16x16x32_bf16(a1, b1, acc, 0, 0, 0);
            acc = __builtin_amdgcn_mfma_f32_16x16x32_bf16(a2, b2, acc, 0, 0, 0);
            acc = __builtin_amdgcn_mfma_f32_16x16x32_bf16(a3, b3, acc, 0, 0, 0);
            int gcol = c * 16 + ocol;
            float bb = bias[gcol];
            #pragma unroll
            for (int j = 0; j < 4; ++j) {
                int row = r0 + orow + j;
                if (row >= n) continue;
                float v = acc[j] + bb;
                if (m == 0) Cq[(size_t)row * 128 + gcol] = v * 0.25f;
                else if (m == 1) store_out(&KV[(size_t)row * 256 + gcol], v);
                else if (m == 2) store_out(&KV[(size_t)row * 256 + 128 + gcol], v);
                else Bb[(size_t)row * 128 + gcol] = v;
            }
        }
    }
}

// ---------------- GCN aggregation: 1 wave/node, prescaled adds, unroll 8 ----------------
// y = relu(dinv[dst] * (xw'[self] + sum_nbrs xw'[s]) + b), bf16 out. xw' prescaled by src dinv.
__global__ __launch_bounds__(256) void k_gcn_agg(const uint* __restrict__ xw, const int* __restrict__ off,
                                                 const int* __restrict__ col, const float* __restrict__ dinv,
                                                 const float* __restrict__ bias, __hip_bfloat162* __restrict__ y, int n) {
    int wid = (blockIdx.x * 256 + threadIdx.x) >> 6;
    int lane = threadIdx.x & 63;
    if (wid >= n) return;
    float di = dinv[wid];
    float2 acc = bf2_unpack(xw[(size_t)wid * 64 + lane]);  // self (prescaled by its dinv)
    int i = off[wid], i1 = off[wid + 1];
    for (; i + 7 < i1; i += 8) {
        uint u0 = xw[(size_t)col[i] * 64 + lane];
        uint u1 = xw[(size_t)col[i + 1] * 64 + lane];
        uint u2 = xw[(size_t)col[i + 2] * 64 + lane];
        uint u3 = xw[(size_t)col[i + 3] * 64 + lane];
        uint u4 = xw[(size_t)col[i + 4] * 64 + lane];
        uint u5 = xw[(size_t)col[i + 5] * 64 + lane];
        uint u6 = xw[(size_t)col[i + 6] * 64 + lane];
        uint u7 = xw[(size_t)col[i + 7] * 64 + lane];
        float2 x0 = bf2_unpack(u0), x1 = bf2_unpack(u1), x2 = bf2_unpack(u2), x3 = bf2_unpack(u3);
        float2 x4 = bf2_unpack(u4), x5 = bf2_unpack(u5), x6 = bf2_unpack(u6), x7 = bf2_unpack(u7);
        acc.x += ((x0.x + x1.x) + (x2.x + x3.x)) + ((x4.x + x5.x) + (x6.x + x7.x));
        acc.y += ((x0.y + x1.y) + (x2.y + x3.y)) + ((x4.y + x5.y) + (x6.y + x7.y));
    }
    for (; i < i1; ++i) {
        float2 x0 = bf2_unpack(xw[(size_t)col[i] * 64 + lane]);
        acc.x += x0.x;
        acc.y += x0.y;
    }
    float2 b2 = ((const float2*)bias)[lane];
    __hip_bfloat162 o;
    o.x = __float2bfloat16(fmaxf(di * acc.x + b2.x, 0.f));
    o.y = __float2bfloat16(fmaxf(di * acc.y + b2.y, 0.f));
    y[(size_t)wid * 64 + lane] = o;
}

// ---------------- transformer attention: 1 wave/dst, 8-edge chunks, single rescale/chunk ----------------
// q pre-scaled by 1/sqrt(16). KV row = 128 uints (k:0..63, v:64..127). lane l holds feats {2l,2l+1};
// head h = l>>3 spans lanes 8h..8h+7.
__global__ __launch_bounds__(256) void k_attn(const float* __restrict__ q, const uint* __restrict__ kv,
                                              const int* __restrict__ off, const int* __restrict__ col,
                                              float* __restrict__ io, int n) {
    int wid = (blockIdx.x * 256 + threadIdx.x) >> 6;
    int lane = threadIdx.x & 63;
    if (wid >= n) return;
    float2 q2 = ((const float2*)(q + (size_t)wid * 128))[lane];
    float m = -INFINITY, s = 0.f;
    float2 acc = make_float2(0.f, 0.f);
    int i = off[wid], i1 = off[wid + 1];
    for (; i + 7 < i1; i += 8) {
        size_t b0 = (size_t)col[i] * 128 + lane;
        size_t b1 = (size_t)col[i + 1] * 128 + lane;
        size_t b2 = (size_t)col[i + 2] * 128 + lane;
        size_t b3 = (size_t)col[i + 3] * 128 + lane;
        size_t b4 = (size_t)col[i + 4] * 128 + lane;
        size_t b5 = (size_t)col[i + 5] * 128 + lane;
        size_t b6 = (size_t)col[i + 6] * 128 + lane;
        size_t b7 = (size_t)col[i + 7] * 128 + lane;
        uint ku0 = kv[b0], ku1 = kv[b1], ku2 = kv[b2], ku3 = kv[b3];
        uint ku4 = kv[b4], ku5 = kv[b5], ku6 = kv[b6], ku7 = kv[b7];
        uint vu0 = kv[b0 + 64], vu1 = kv[b1 + 64], vu2 = kv[b2 + 64], vu3 = kv[b3 + 64];
        uint vu4 = kv[b4 + 64], vu5 = kv[b5 + 64], vu6 = kv[b6 + 64], vu7 = kv[b7 + 64];
        float2 k0 = bf2_unpack(ku0), k1 = bf2_unpack(ku1), k2 = bf2_unpack(ku2), k3 = bf2_unpack(ku3);
        float2 k4 = bf2_unpack(ku4), k5 = bf2_unpack(ku5), k6 = bf2_unpack(ku6), k7 = bf2_unpack(ku7);
        float l0 = q2.x * k0.x + q2.y * k0.y;
        float l1 = q2.x * k1.x + q2.y * k1.y;
        float l2 = q2.x * k2.x + q2.y * k2.y;
        float l3 = q2.x * k3.x + q2.y * k3.y;
        float l4 = q2.x * k4.x + q2.y * k4.y;
        float l5 = q2.x * k5.x + q2.y * k5.y;
        float l6 = q2.x * k6.x + q2.y * k6.y;
        float l7 = q2.x * k7.x + q2.y * k7.y;
        l0 += __shfl_xor(l0, 1); l1 += __shfl_xor(l1, 1); l2 += __shfl_xor(l2, 1); l3 += __shfl_xor(l3, 1);
        l4 += __shfl_xor(l4, 1); l5 += __shfl_xor(l5, 1); l6 += __shfl_xor(l6, 1); l7 += __shfl_xor(l7, 1);
        l0 += __shfl_xor(l0, 2); l1 += __shfl_xor(l1, 2); l2 += __shfl_xor(l2, 2); l3 += __shfl_xor(l3, 2);
        l4 += __shfl_xor(l4, 2); l5 += __shfl_xor(l5, 2); l6 += __shfl_xor(l6, 2); l7 += __shfl_xor(l7, 2);
        l0 += __shfl_xor(l0, 4); l1 += __shfl_xor(l1, 4); l2 += __shfl_xor(l2, 4); l3 += __shfl_xor(l3, 4);
        l4 += __shfl_xor(l4, 4); l5 += __shfl_xor(l5, 4); l6 += __shfl_xor(l6, 4); l7 += __shfl_xor(l7, 4);
        float mx = fmaxf(fmaxf(fmaxf(l0, l1), fmaxf(l2, l3)), fmaxf(fmaxf(l4, l5), fmaxf(l6, l7)));
        if (mx > m) {                         // rescale once per 8-edge chunk
            float corr = __expf(m - mx);      // 0 on first chunk (m=-inf)
            s *= corr;
            acc.x *= corr;
            acc.y *= corr;
            m = mx;
        }
        float e0 = __expf(l0 - m), e1 = __expf(l1 - m), e2 = __expf(l2 - m), e3 = __expf(l3 - m);
        float e4 = __expf(l4 - m), e5 = __expf(l5 - m), e6 = __expf(l6 - m), e7 = __expf(l7 - m);
        s += ((e0 + e1) + (e2 + e3)) + ((e4 + e5) + (e6 + e7));
        float2 v0 = bf2_unpack(vu0), v1 = bf2_unpack(vu1), v2 = bf2_unpack(vu2), v3 = bf2_unpack(vu3);
        float2 v4 = bf2_unpack(vu4), v5 = bf2_unpack(vu5), v6 = bf2_unpack(vu6), v7 = bf2_unpack(vu7);
        acc.x += ((e0 * v0.x + e1 * v1.x) + (e2 * v2.x + e3 * v3.x)) + ((e4 * v4.x + e5 * v5.x) + (e6 * v6.x + e7 * v7.x));
        acc.y += ((e0 * v0.y + e1 * v1.y) + (e2 * v2.y + e3 * v3.y)) + ((e4 * v4.y + e5 * v5.y) + (e6 * v6.y + e7 * v7.y));
    }
    for (; i < i1; ++i) {
        size_t b0 = (size_t)col[i] * 128 + lane;
        uint ku0 = kv[b0];
        uint vu0 = kv[b0 + 64];
        float2 k0 = bf2_unpack(ku0);
        float l0 = q2.x * k0.x + q2.y * k0.y;
        l0 += __shfl_xor(l0, 1);
        l0 += __shfl_xor(l0, 2);
        l0 += __shfl_xor(l0, 4);
        if (l0 > m) {
            float corr = __expf(m - l0);
            s *= corr;
            acc.x *= corr;
            acc.y *= corr;
            m = l0;
        }
        float e0 = __expf(l0 - m);
        s += e0;
        float2 v0 = bf2_unpack(vu0);
        acc.x += e0 * v0.x;
        acc.y += e0 * v0.y;
    }
    float inv = 1.f / fmaxf(s, 1e-16f);
    float2* orow = (float2*)(io + (size_t)wid * 128);
    float2 o2 = orow[lane];               // skip connection already there
    o2.x += acc.x * inv;
    o2.y += acc.y * inv;
    orow[lane] = o2;
}

// ---------------- mean-pool per graph (batch sorted), 64 nodes/block ----------------
__global__ __launch_bounds__(128) void k_pool(const float* __restrict__ x, const int* __restrict__ batch,
                                              float* __restrict__ gsum, float* __restrict__ cnt, int n) {
    int t = threadIdx.x;
    int start = blockIdx.x * 64;
    int end = start + 64; if (end > n) end = n;
    if (start >= n) return;
    int cur = batch[start];
    float acc = 0.f;
    int run = 0;
    for (int nn = start; nn < end; ++nn) {
        int g = batch[nn];
        if (g != cur) {
            atomicAdd(&gsum[cur * 128 + t], acc);
            if (t == 0) atomicAdd(&cnt[cur], (float)run);
            acc = 0.f; run = 0; cur = g;
        }
        acc += x[(size_t)nn * 128 + t];
        run++;
    }
    atomicAdd(&gsum[cur * 128 + t], acc);
    if (t == 0) atomicAdd(&cnt[cur], (float)run);
}

// ---------------- FiLM + LSTM + LayerNorm + dueling heads, one block per graph ----------------
__global__ __launch_bounds__(128) void k_final(
    const float* __restrict__ gsum, const float* __restrict__ cnt, const float* __restrict__ w,
    const float* __restrict__ Wgam, const float* __restrict__ bgam,
    const float* __restrict__ Wbet, const float* __restrict__ bbet,
    const float* __restrict__ hprev, const float* __restrict__ cprev,
    const float* __restrict__ Wih, const float* __restrict__ bih,
    const float* __restrict__ Whh, const float* __restrict__ bhh,
    const float* __restrict__ lng, const float* __restrict__ lnb,
    const float* __restrict__ Wa1, const float* __restrict__ ba1,
    const float* __restrict__ Wa2, const float* __restrict__ ba2,
    const float* __restrict__ Wv1, const float* __restrict__ bv1,
    const float* __restrict__ Wv2, const float* __restrict__ bv2,
    float* __restrict__ out_qv, float* __restrict__ out_h, float* __restrict__ out_c) {
    int g = blockIdx.x, t = threadIdx.x;
    __shared__ __align__(16) float ge[128], hp[128], hn[128], r1[128], a1s[128], red[128];
    __shared__ float adv[16], val[2], mu_s, var_s;

    float w0 = w[g * 2 + 0], w1 = w[g * 2 + 1];
    float c = fmaxf(cnt[g], 1.f);
    float mn = gsum[g * 128 + t] / c;
    float gam = w0 * Wgam[2 * t] + w1 * Wgam[2 * t + 1] + bgam[t];
    float bet = w0 * Wbet[2 * t] + w1 * Wbet[2 * t + 1] + bbet[t];
    ge[t] = (1.f + gam) * mn + bet;
    hp[t] = hprev[g * 128 + t];
    __syncthreads();

    float gi = bih[t] + bhh[t];
    float gf = bih[128 + t] + bhh[128 + t];
    float gg = bih[256 + t] + bhh[256 + t];
    float go = bih[384 + t] + bhh[384 + t];
    {
        const float4* ge4 = (const float4*)ge;
        const float4* hp4 = (const float4*)hp;
        const float4* Ai = (const float4*)(Wih + (size_t)t * 128);
        const float4* Af = (const float4*)(Wih + (size_t)(128 + t) * 128);
        const float4* Ag = (const float4*)(Wih + (size_t)(256 + t) * 128);
        const float4* Ao = (const float4*)(Wih + (size_t)(384 + t) * 128);
        const float4* Hi = (const float4*)(Whh + (size_t)t * 128);
        const float4* Hf = (const float4*)(Whh + (size_t)(128 + t) * 128);
        const float4* Hg = (const float4*)(Whh + (size_t)(256 + t) * 128);
        const float4* Ho = (const float4*)(Whh + (size_t)(384 + t) * 128);
        #pragma unroll 4
        for (int k4 = 0; k4 < 32; ++k4) {
            float4 a = ge4[k4], h4 = hp4[k4], u;
            u = Ai[k4]; gi += a.x * u.x + a.y * u.y + a.z * u.z + a.w * u.w;
            u = Hi[k4]; gi += h4.x * u.x + h4.y * u.y + h4.z * u.z + h4.w * u.w;
            u = Af[k4]; gf += a.x * u.x + a.y * u.y + a.z * u.z + a.w * u.w;
            u = Hf[k4]; gf += h4.x * u.x + h4.y * u.y + h4.z * u.z + h4.w * u.w;
            u = Ag[k4]; gg += a.x * u.x + a.y * u.y + a.z * u.z + a.w * u.w;
            u = Hg[k4]; gg += h4.x * u.x + h4.y * u.y + h4.z * u.z + h4.w * u.w;
            u = Ao[k4]; go += a.x * u.x + a.y * u.y + a.z * u.z + a.w * u.w;
            u = Ho[k4]; go += h4.x * u.x + h4.y * u.y + h4.z * u.z + h4.w * u.w;
        }
    }
    float ig = 1.f / (1.f + __expf(-gi));
    float fg = 1.f / (1.f + __expf(-gf));
    float gc = tanhf(gg);
    float og = 1.f / (1.f + __expf(-go));
    float craw = fg * cprev[g * 128 + t] + ig * gc;
    float hraw = og * tanhf(craw);
    out_c[g * 128 + t] = fminf(fmaxf(craw, -1e6f), 1e6f);

    red[t] = hraw;
    __syncthreads();
    for (int s2 = 64; s2 > 0; s2 >>= 1) { if (t < s2) red[t] += red[t + s2]; __syncthreads(); }
    if (t == 0) mu_s = red[0] * (1.f / 128.f);
    __syncthreads();
    float mu = mu_s;
    float d = hraw - mu;
    red[t] = d * d;
    __syncthreads();
    for (int s2 = 64; s2 > 0; s2 >>= 1) { if (t < s2) red[t] += red[t + s2]; __syncthreads(); }
    if (t == 0) var_s = red[0] * (1.f / 128.f);
    __syncthreads();
    float hv = d * rsqrtf(var_s + 1e-5f) * lng[t] + lnb[t];
    hn[t] = hv;
    out_h[g * 128 + t] = hv;
    __syncthreads();

    float accv = bv1[t], acca = ba1[t];
    {
        const float4* hn4 = (const float4*)hn;
        const float4* V1 = (const float4*)(Wv1 + (size_t)t * 128);
        const float4* A1 = (const float4*)(Wa1 + (size_t)t * 128);
        #pragma unroll 4
        for (int k4 = 0; k4 < 32; ++k4) {
            float4 hh = hn4[k4], u;
            u = V1[k4]; accv += hh.x * u.x + hh.y * u.y + hh.z * u.z + hh.w * u.w;
            u = A1[k4]; acca += hh.x * u.x + hh.y * u.y + hh.z * u.z + hh.w * u.w;
        }
    }
    r1[t] = fmaxf(accv, 0.f);
    a1s[t] = fmaxf(acca, 0.f);
    __syncthreads();
    if (t < 2) {
        float s = bv2[t];
        const float4* V2 = (const float4*)(Wv2 + (size_t)t * 128);
        const float4* r4 = (const float4*)r1;
        for (int k4 = 0; k4 < 32; ++k4) { float4 u = V2[k4], rr = r4[k4]; s += rr.x * u.x + rr.y * u.y + rr.z * u.z + rr.w * u.w; }
        val[t] = s;
    }
    if (t < 14) {
        float s = ba2[t];
        const float4* A2 = (const float4*)(Wa2 + (size_t)t * 128);
        const float4* a4 = (const float4*)a1s;
        for (int k4 = 0; k4 < 32; ++k4) { float4 u = A2[k4], aa = a4[k4]; s += aa.x * u.x + aa.y * u.y + aa.z * u.z + aa.w * u.w; }
        adv[t] = s;
    }
    __syncthreads();
    if (t < 14) {
        int o = t & 1;
        float mo = (adv[o] + adv[o + 2] + adv[o + 4] + adv[o + 6] + adv[o + 8] + adv[o + 10] + adv[o + 12]) * (1.f / 7.f);
        float qq = val[o] + adv[t] - mo;
        if (isnan(qq)) qq = 0.f;
        qq = fminf(fmaxf(qq, -100.f), 100.f);
        out_qv[g * 14 + t] = qq;
    }
}

extern "C" void kernel_launch(void* const* d_in, const int* in_sizes, int n_in,
                              void* d_out, int out_size, void* d_ws, size_t ws_size,
                              hipStream_t stream) {
    const float* nf    = (const float*)d_in[0];
    const int*   ei    = (const int*)d_in[1];
    const int*   batch = (const int*)d_in[2];
    const float* w     = (const float*)d_in[3];
    const float* hprev = (const float*)d_in[4];
    const float* cprev = (const float*)d_in[5];
    const float* W_emb = (const float*)d_in[6];  const float* b_emb = (const float*)d_in[7];
    const float* W_g1  = (const float*)d_in[8];  const float* b_g1  = (const float*)d_in[9];
    const float* W_g2  = (const float*)d_in[10]; const float* b_g2  = (const float*)d_in[11];
    const float* Wq    = (const float*)d_in[12]; const float* bq    = (const float*)d_in[13];
    const float* Wk    = (const float*)d_in[14]; const float* bk    = (const float*)d_in[15];
    const float* Wv    = (const float*)d_in[16]; const float* bv    = (const float*)d_in[17];
    const float* Wskip = (const float*)d_in[18]; const float* bskip = (const float*)d_in[19];
    const float* Wgam  = (const float*)d_in[20]; const float* bgam  = (const float*)d_in[21];
    const float* Wbet  = (const float*)d_in[22]; const float* bbet  = (const float*)d_in[23];
    const float* Wih   = (const float*)d_in[24]; const float* bih   = (const float*)d_in[25];
    const float* Whh   = (const float*)d_in[26]; const float* bhh   = (const float*)d_in[27];
    const float* lng   = (const float*)d_in[28]; const float* lnb   = (const float*)d_in[29];
    const float* Wa1   = (const float*)d_in[30]; const float* ba1   = (const float*)d_in[31];
    const float* Wa2   = (const float*)d_in[32]; const float* ba2   = (const float*)d_in[33];
    const float* Wv1   = (const float*)d_in[34]; const float* bv1   = (const float*)d_in[35];
    const float* Wv2   = (const float*)d_in[36]; const float* bv2   = (const float*)d_in[37];

    int N = in_sizes[2];
    int E = in_sizes[1] / 2;
    int B = in_sizes[4] / 128;

    char* p = (char*)d_ws;
    auto alloc = [&](size_t bytes) { char* r = p; p += (bytes + 511) & ~(size_t)511; return r; };
    int*   indeg  = (int*)alloc((size_t)N * 4);
    int*   cursor = (int*)alloc((size_t)N * 4);
    float* gsum   = (float*)alloc((size_t)B * 128 * 4);
    float* cnt    = (float*)alloc((size_t)B * 4);
    size_t zbytes = (size_t)(p - (char*)d_ws);   // region zeroed each call
    int*   off    = (int*)alloc((size_t)(N + 1) * 4);
    int*   col    = (int*)alloc((size_t)E * 4);
    float* dinv   = (float*)alloc((size_t)N * 4);
    __hip_bfloat16* Wc  = (__hip_bfloat16*)alloc((size_t)6 * 16384 * 2);  // bf16 weights: g1,g2,q,k,v,skip
    __hip_bfloat16* X0b = (__hip_bfloat16*)alloc((size_t)N * 128 * 2);    // x0 / x2
    __hip_bfloat16* X1b = (__hip_bfloat16*)alloc((size_t)N * 128 * 2);    // x1
    __hip_bfloat16* XWb = (__hip_bfloat16*)alloc((size_t)N * 128 * 2);    // xw scratch (prescaled)
    __hip_bfloat16* KV  = (__hip_bfloat16*)alloc((size_t)N * 256 * 2);    // interleaved k|v
    float* Cq = (float*)alloc((size_t)N * 128 * 4);
    float* Bb = (float*)alloc((size_t)N * 128 * 4);
    if ((size_t)(p - (char*)d_ws) > ws_size) return;

    hipMemsetAsync(d_ws, 0, zbytes, stream);

    const __hip_bfloat16* Wg1b  = Wc + 0 * 16384;
    const __hip_bfloat16* Wg2b  = Wc + 1 * 16384;
    const __hip_bfloat16* Wqkvs = Wc + 2 * 16384;   // q,k,v,skip contiguous
    k_cvt6<<<384, 256, 0, stream>>>(W_g1, W_g2, Wq, Wk, Wv, Wskip, Wc);

    int gE = (E + 255) / 256;
    k_count<<<gE, 256, 0, stream>>>(ei, indeg, E);
    k_scan<<<1, 1024, 0, stream>>>(indeg, off, N);
    k_fill<<<gE, 256, 0, stream>>>(ei, off, cursor, col, E);
    k_dinv<<<(N + 255) / 256, 256, 0, stream>>>(indeg, dinv, N);

    int gN = (N + 3) / 4;       // gather kernels: 4 waves/block, 1 node/wave
    int gM = (N + 63) / 64;     // MFMA kernels: 64 rows/block

    k_linear<32, true, true, __hip_bfloat16><<<2048, 256, 0, stream>>>(nf, W_emb, b_emb, X0b, N);   // x0 bf16
    k_lin_mfma_scale<<<gM, 256, 0, stream>>>(X0b, Wg1b, dinv, XWb, N);                              // xw1' = xw1*dinv
    k_gcn_agg<<<gN, 256, 0, stream>>>((const uint*)XWb, off, col, dinv, b_g1, (__hip_bfloat162*)X1b, N); // x1
    k_lin_mfma_scale<<<gM, 256, 0, stream>>>(X1b, Wg2b, dinv, XWb, N);                              // xw2'
    k_gcn_agg<<<gN, 256, 0, stream>>>((const uint*)XWb, off, col, dinv, b_g2, (__hip_bfloat162*)X0b, N); // x2

    k_qkvs_mfma<<<gM, 256, 0, stream>>>(X0b, Wqkvs, bq, bk, bv, bskip, Cq, KV, Bb, N);              // q,KV,skip
    k_attn<<<gN, 256, 0, stream>>>(Cq, (const uint*)KV, off, col, Bb, N);                           // Bb += attn

    k_pool<<<gM, 128, 0, stream>>>(Bb, batch, gsum, cnt, N);

    float* out_qv = (float*)d_out;
    float* out_h  = out_qv + (size_t)B * 14;
    float* out_c  = out_h + (size_t)B * 128;
    k_final<<<B, 128, 0, stream>>>(gsum, cnt, w, Wgam, bgam, Wbet, bbet, hprev, cprev,
                                   Wih, bih, Whh, bhh, lng, lnb,
                                   Wa1, ba1, Wa2, ba2, Wv1, bv1, Wv2, bv2,
                                   out_qv, out_h, out_c);
}